// Round 3
// baseline (85.425 us; speedup 1.0000x reference)
//
#include <hip/hip_runtime.h>
#include <math.h>

#define DIM     1024
#define NSTAGES 10
#define HALFD   512                   // angles per stage = DIM/2
#define TABN    (NSTAGES * HALFD)     // 5120 floats per table

typedef float v4f __attribute__((ext_vector_type(4)));

// ---------------------------------------------------------------------------
// Prep: cos/sin tables into workspace. ws layout: cos[10][512] | sin[10][512]
// ---------------------------------------------------------------------------
__global__ void bf_prep(const float* __restrict__ ang, float* __restrict__ ws) {
    int i = blockIdx.x * blockDim.x + threadIdx.x;
    if (i < TABN) {
        float s, c;
        sincosf(ang[i], &s, &c);
        ws[i]        = c;
        ws[TABN + i] = s;
    }
}

// ---------------------------------------------------------------------------
// Per-row butterfly on 16 register-resident floats (4 x float4).
// Lane owns elements e = 256*c + 4*lane + d.
//   stage 0,1  : intra-float4
//   stage 2..7 : cross-lane, shfl_xor mask m = 1<<(s-2)  (1..32)
//   stage 8,9  : intra-lane across c-groups
// Angle index for left element i at stage s: p = ((i>>(s+1))<<s) | (i&(half-1))
// ---------------------------------------------------------------------------
__device__ __forceinline__ void processRow(float4 v[4],
                                           const float* __restrict__ cosT,
                                           const float* __restrict__ sinT,
                                           int lane)
{
    // ---- stages 0,1: intra-float4. p = 128c + 2*lane + {0,1} -------------
    #pragma unroll
    for (int s01 = 0; s01 < 2; ++s01) {
        const float* cT = cosT + s01 * HALFD;
        const float* sT = sinT + s01 * HALFD;
        #pragma unroll
        for (int c = 0; c < 4; ++c) {
            const int p = 128 * c + 2 * lane;
            float2 cc = *(const float2*)&cT[p];
            float2 ss = *(const float2*)&sT[p];
            float4 u = v[c];
            if (s01 == 0) {
                v[c].x = cc.x * u.x + ss.x * u.y;
                v[c].y = cc.x * u.y - ss.x * u.x;
                v[c].z = cc.y * u.z + ss.y * u.w;
                v[c].w = cc.y * u.w - ss.y * u.z;
            } else {
                v[c].x = cc.x * u.x + ss.x * u.z;
                v[c].z = cc.x * u.z - ss.x * u.x;
                v[c].y = cc.y * u.y + ss.y * u.w;
                v[c].w = cc.y * u.w - ss.y * u.y;
            }
        }
    }

    // ---- stages 2..7: cross-lane via shfl_xor ----------------------------
    #pragma unroll
    for (int s = 2; s <= 7; ++s) {
        const int m = 1 << (s - 2);
        const float* cT = cosT + s * HALFD;
        const float* sT = sinT + s * HALFD;
        const int l0 = lane & ~m;                  // left lane of the pair
        const float sgn = (lane & m) ? -1.0f : 1.0f;
        #pragma unroll
        for (int c = 0; c < 4; ++c) {
            const int p0 = (((c << (7 - s)) + (l0 >> (s - 1))) << s)
                         + 4 * (l0 & (m - 1));
            float4 C = *(const float4*)&cT[p0];
            float4 S = *(const float4*)&sT[p0];
            S.x *= sgn; S.y *= sgn; S.z *= sgn; S.w *= sgn;
            float4 u = v[c];
            float tx = __shfl_xor(u.x, m, 64);
            float ty = __shfl_xor(u.y, m, 64);
            float tz = __shfl_xor(u.z, m, 64);
            float tw = __shfl_xor(u.w, m, 64);
            v[c].x = C.x * u.x + S.x * tx;
            v[c].y = C.y * u.y + S.y * ty;
            v[c].z = C.z * u.z + S.z * tz;
            v[c].w = C.w * u.w + S.w * tw;
        }
    }

    // ---- stage 8: pairs (c0,c1),(c2,c3); p = 256*g + 4*lane + d ----------
    {
        const float* cT = cosT + 8 * HALFD;
        const float* sT = sinT + 8 * HALFD;
        #pragma unroll
        for (int g = 0; g < 2; ++g) {
            const int p0 = 256 * g + 4 * lane;
            float4 C = *(const float4*)&cT[p0];
            float4 S = *(const float4*)&sT[p0];
            float4 L = v[2 * g], Rr = v[2 * g + 1];
            v[2 * g].x     = C.x * L.x + S.x * Rr.x;
            v[2 * g].y     = C.y * L.y + S.y * Rr.y;
            v[2 * g].z     = C.z * L.z + S.z * Rr.z;
            v[2 * g].w     = C.w * L.w + S.w * Rr.w;
            v[2 * g + 1].x = C.x * Rr.x - S.x * L.x;
            v[2 * g + 1].y = C.y * Rr.y - S.y * L.y;
            v[2 * g + 1].z = C.z * Rr.z - S.z * L.z;
            v[2 * g + 1].w = C.w * Rr.w - S.w * L.w;
        }
    }

    // ---- stage 9: pairs (c0,c2),(c1,c3) ----------------------------------
    {
        const float* cT = cosT + 9 * HALFD;
        const float* sT = sinT + 9 * HALFD;
        #pragma unroll
        for (int g = 0; g < 2; ++g) {
            const int p0 = 256 * g + 4 * lane;
            float4 C = *(const float4*)&cT[p0];
            float4 S = *(const float4*)&sT[p0];
            float4 L = v[g], Rr = v[g + 2];
            v[g].x     = C.x * L.x + S.x * Rr.x;
            v[g].y     = C.y * L.y + S.y * Rr.y;
            v[g].z     = C.z * L.z + S.z * Rr.z;
            v[g].w     = C.w * L.w + S.w * Rr.w;
            v[g + 2].x = C.x * Rr.x - S.x * L.x;
            v[g + 2].y = C.y * Rr.y - S.y * L.y;
            v[g + 2].z = C.z * Rr.z - S.z * L.z;
            v[g + 2].w = C.w * Rr.w - S.w * L.w;
        }
    }
}

__device__ __forceinline__ void loadRow(const float4* __restrict__ xp, float4 v[4]) {
    v[0] = xp[0];
    v[1] = xp[64];
    v[2] = xp[128];
    v[3] = xp[192];
}

__device__ __forceinline__ void storeRow(float4* __restrict__ op, const float4 v[4]) {
    v4f* p = (v4f*)op;
    #pragma unroll
    for (int c = 0; c < 4; ++c) {
        v4f t = { v[c].x, v[c].y, v[c].z, v[c].w };
        __builtin_nontemporal_store(t, p + 64 * c);
    }
}

// ---------------------------------------------------------------------------
// Main: 1024 blocks x 4 waves; each wave pipelines 4 rows (stride = #waves).
// Row-0 loads issued BEFORE table staging; row i+1 loads before compute(i).
// ---------------------------------------------------------------------------
__global__ __launch_bounds__(256) void bf_main(
    const float* __restrict__ x,
    const float* __restrict__ tab,
    float* __restrict__ out,
    int nrows)
{
    __shared__ __align__(16) float cosT[TABN];
    __shared__ __align__(16) float sinT[TABN];
    const int tid  = threadIdx.x;
    const int lane = tid & 63;
    const int gwid = blockIdx.x * 4 + (tid >> 6);   // global wave id, [0, nrows/4)
    const int wstride = nrows >> 2;                 // rows between iterations

    const size_t fstride = (size_t)wstride * (DIM / 4);   // float4 stride/iter
    const float4* xp = ((const float4*)(x   + (size_t)gwid * DIM)) + lane;
    float4*       op = ((float4*)      (out + (size_t)gwid * DIM)) + lane;

    float4 A[4], B[4];

    // row 0 loads in flight while we stage the tables
    loadRow(xp, A);

    {   // stage cos/sin tables: 40 KB, 10 float4s per thread
        const float4* s4 = (const float4*)tab;
        float4* c4 = (float4*)cosT;
        float4* n4 = (float4*)sinT;
        #pragma unroll
        for (int i = 0; i < TABN / 4 / 256; ++i) {   // 5 iterations
            const int idx = i * 256 + tid;
            c4[idx] = s4[idx];
            n4[idx] = s4[TABN / 4 + idx];
        }
    }
    __syncthreads();

    // software pipeline over 4 rows: load(i+1) issued before process(i)
    loadRow(xp + fstride, B);
    processRow(A, cosT, sinT, lane);
    storeRow(op, A);

    loadRow(xp + 2 * fstride, A);
    processRow(B, cosT, sinT, lane);
    storeRow(op + fstride, B);

    loadRow(xp + 3 * fstride, B);
    processRow(A, cosT, sinT, lane);
    storeRow(op + 2 * fstride, A);

    processRow(B, cosT, sinT, lane);
    storeRow(op + 3 * fstride, B);
}

extern "C" void kernel_launch(void* const* d_in, const int* in_sizes, int n_in,
                              void* d_out, int out_size, void* d_ws, size_t ws_size,
                              hipStream_t stream) {
    const float* x   = (const float*)d_in[0];
    const float* ang = (const float*)d_in[1];
    float* out = (float*)d_out;

    const int nrows  = out_size / DIM;        // 16384
    // 4 waves/block, 4 rows/wave -> 16 rows/block; 16384/16 = 1024 blocks
    const int nblocks = nrows / 16;

    float* tab = (float*)d_ws;                // 40 KB, ws is plenty
    bf_prep<<<(TABN + 255) / 256, 256, 0, stream>>>(ang, tab);
    bf_main<<<nblocks, 256, 0, stream>>>(x, tab, out, nrows);
}